// Round 7
// baseline (5194.739 us; speedup 1.0000x reference)
//
#include <hip/hip_runtime.h>

// B=2048, T=128, N=64, H=128
// inputs: 0 X(2048,128,64) 1 W_attn1(128,384) 2 b_attn1(128) 3 w_attn2(128)
//         4 b_attn2(1)[unused] 5 W_ih(512,64) 6 W_hh(512,128) 7 b_ih(512) 8 b_hh(512)
// output: (2048,128,128) f32
// ws (floats): Wt[128][128] @0 | W1P[128][64][4] @16384 | Wp4[48][128][4][4] @49152 | prex @147456
//
// R7: R5's proven memory regime (px in LDS; weights stream L2-hot) + R6's
// instruction diet. Every global access = single contiguous >=512B segment
// per wave (R6's 4-segment loads/stores caused 7.9GB HBM fetch + 775MB RMW
// writes). P4 reduces c-slices via DPP shfl (no LDS roundtrip), state in regs.

typedef float f32x4 __attribute__((ext_vector_type(4)));
typedef float f32x2 __attribute__((ext_vector_type(2)));

#define LOG2E 1.44269504088896340736f
__device__ __forceinline__ float rcpf(float x){ return __builtin_amdgcn_rcpf(x); }
__device__ __forceinline__ float fast_exp(float x){ return __builtin_exp2f(x * LOG2E); }
__device__ __forceinline__ float fast_tanh(float x){
  float e = __builtin_exp2f(x * (2.0f * LOG2E));
  return 1.0f - 2.0f * rcpf(e + 1.0f);
}
__device__ __forceinline__ float fast_sig(float x){
  float e = __builtin_exp2f(x * (-LOG2E));
  return rcpf(1.0f + e);
}
__device__ __forceinline__ float sx(float v, int m){ return __shfl_xor(v, m, 64); }
__device__ __forceinline__ f32x4 sx4(f32x4 v, int m){
  f32x4 r; r.x = sx(v.x,m); r.y = sx(v.y,m); r.z = sx(v.z,m); r.w = sx(v.w,m); return r;
}

// ---- packs ----
__global__ __launch_bounds__(256) void k0_wt(const float* __restrict__ Wat, float* __restrict__ Wt){
  int idx = blockIdx.x*256 + threadIdx.x;   // 16384
  int t = idx >> 7, k = idx & 127;
  Wt[idx] = Wat[k*384 + 256 + t];
}
// W1P[c2][kp][4]: e={c-lo/hi x k-lo/hi}; c=c2*2+(e>>1) in [0,256), k=kp*2+(e&1)
__global__ __launch_bounds__(256) void k0_w1p(const float* __restrict__ Wat, float* __restrict__ W1P){
  int idx = blockIdx.x*256 + threadIdx.x;   // 32768
  int e = idx & 3, kp = (idx>>2) & 63, c2 = idx >> 8;
  int c = c2*2 + (e>>1), k = kp*2 + (e&1);
  W1P[idx] = Wat[k*384 + c];
}
// Wp4[cp][j][cs][q] = W_q[g=q*128+j][c=cs*48+cp]  (c<64 -> Wih, else Whh)
__global__ __launch_bounds__(256) void k0_wp4(const float* __restrict__ Wih, const float* __restrict__ Whh,
                                              float* __restrict__ Wp4){
  int idx = blockIdx.x*256 + threadIdx.x;   // 98304
  int q = idx & 3, cs = (idx>>2) & 3, j = (idx>>4) & 127, cp = idx >> 11;
  int c = cs*48 + cp, g = q*128 + j;
  Wp4[idx] = (c < 64) ? Wih[g*64 + c] : Whh[g*128 + (c-64)];
}

// ---- k1: prex[b][n][k] = sum_t X[b][t][n]*W1x[k][t] + b1[k] ----
__global__ __launch_bounds__(256) void k1_prex(const float* __restrict__ X,
                                               const float* __restrict__ Wt,
                                               const float* __restrict__ b1,
                                               float* __restrict__ prex){
  __shared__ float Xs[128][64];
  const int tid = threadIdx.x;
  const long b = blockIdx.x;
  {
    const float4* X4 = (const float4*)(X + b*8192);
    float4* Xs4 = (float4*)&Xs[0][0];
    #pragma unroll
    for (int i=0;i<8;i++) Xs4[tid + i*256] = X4[tid + i*256];
  }
  __syncthreads();
  const int nq = tid >> 4, kq = tid & 15;
  float acc[4][8];
  #pragma unroll
  for (int n=0;n<4;n++)
    #pragma unroll
    for (int k=0;k<8;k++) acc[n][k]=0.f;
  #pragma unroll 4
  for (int t=0;t<128;t++){
    float4 w0 = *(const float4*)(Wt + t*128 + kq*8);
    float4 w1 = *(const float4*)(Wt + t*128 + kq*8 + 4);
    float4 xv = *(const float4*)&Xs[t][nq*4];
    float wv[8] = {w0.x,w0.y,w0.z,w0.w,w1.x,w1.y,w1.z,w1.w};
    float xa[4] = {xv.x,xv.y,xv.z,xv.w};
    #pragma unroll
    for (int n=0;n<4;n++)
      #pragma unroll
      for (int k=0;k<8;k++) acc[n][k] = fmaf(xa[n], wv[k], acc[n][k]);
  }
  float4 bv0 = *(const float4*)(b1 + kq*8);
  float4 bv1 = *(const float4*)(b1 + kq*8 + 4);
  #pragma unroll
  for (int n=0;n<4;n++){
    float* dst = prex + (b*64 + nq*4 + n)*128 + kq*8;
    *(float4*)(dst)   = make_float4(acc[n][0]+bv0.x, acc[n][1]+bv0.y,
                                    acc[n][2]+bv0.z, acc[n][3]+bv0.w);
    *(float4*)(dst+4) = make_float4(acc[n][4]+bv1.x, acc[n][5]+bv1.y,
                                    acc[n][6]+bv1.z, acc[n][7]+bv1.w);
  }
}

// ---- k2: 512 blocks x 512 threads, 4 batches/block ----
__global__ __launch_bounds__(512, 2)
void k2_lstm(const float* __restrict__ X,
             const float* __restrict__ W1P,
             const float* __restrict__ Wp4,
             const float* __restrict__ w2,
             const float* __restrict__ bih,
             const float* __restrict__ bhh,
             const float* __restrict__ prex,
             float* __restrict__ out)
{
  const int tid = threadIdx.x;
  const long b0 = (long)blockIdx.x * 4;

  __shared__ float px[4][64][128];   // 128 KB
  __shared__ float aap[8][4][128];   // P1 partials [wave][b][k]  16 KB
  __shared__ float epp[4][64][8];    // P2 partials                8 KB
  __shared__ float actc[4][192];     // [0,64)=x_tilde, [64,192)=h 3 KB
  __shared__ float csd[4][128];      // c-state (for P1)           2 KB

  // ---- px slice -> LDS (linear, coalesced)
  {
    const f32x4* pg = (const f32x4*)prex + b0*2048;
    f32x4* pl = (f32x4*)&px[0][0][0];
    #pragma unroll
    for (int i = 0; i < 16; ++i) pl[tid + i*512] = pg[tid + i*512];
  }

  const int w = tid >> 6, l = tid & 63;

  // P1 roles: wave w owns c-slice [w*32,(w+1)*32); lane = k-pair
  const float* p1w = W1P + (w*16)*256 + l*4;
  const float* p1src; int p1str;
  if (w < 4) { p1src = &actc[0][64 + w*32]; p1str = 192; }
  else       { p1src = &csd[0][(w-4)*32];   p1str = 128; }

  // P2 roles
  const int p2b = tid >> 7, p2ns = (tid >> 5) & 3, p2kq = tid & 31;
  const f32x4 w2v = *(const f32x4*)(w2 + p2kq*4);

  // P4 roles: lane = (cs, jl); j = w*16 + jl
  const int p4cs = l & 3, p4jl = l >> 2, p4j = w*16 + p4jl;
  const float* p4w = Wp4 + p4j*16 + p4cs*4;
  const float bq0 = bih[p4j]       + bhh[p4j];
  const float bq1 = bih[p4j + 128] + bhh[p4j + 128];
  const float bq2 = bih[p4j + 256] + bhh[p4j + 256];
  const float bq3 = bih[p4j + 384] + bhh[p4j + 384];

  // out/state maps
  const int ob = tid >> 7, oj = tid & 127;

  float cre = 0.f, hn = 0.f;   // persistent state of (batch p4cs, unit p4j)
  float xreg = 0.f;

  // publish initial (zero) state
  csd[p4cs][p4j] = cre;
  actc[p4cs][64 + p4j] = hn;
  __syncthreads();

  for (int t = 0; t < 128; ++t) {
    // ---------- P1 (+ deferred out-write + X prefetch)
    if (t > 0) out[(b0+ob)*16384 + (long)(t-1)*128 + oj] = actc[ob][64 + oj];
    if (tid < 256) xreg = X[(b0 + (tid>>6))*8192 + (long)t*64 + (tid & 63)];
    {
      f32x2 a0, a1, a2, a3;
      a0 = 0.f; a1 = 0.f; a2 = 0.f; a3 = 0.f;
      #pragma unroll
      for (int o = 0; o < 8; ++o) {
        f32x4 wq0 = *(const f32x4*)(p1w + (2*o  )*256);
        f32x4 wq1 = *(const f32x4*)(p1w + (2*o+1)*256);
        f32x4 v0 = *(const f32x4*)(p1src + 0*p1str + o*4);
        f32x4 v1 = *(const f32x4*)(p1src + 1*p1str + o*4);
        f32x4 v2 = *(const f32x4*)(p1src + 2*p1str + o*4);
        f32x4 v3 = *(const f32x4*)(p1src + 3*p1str + o*4);
        a0.x = fmaf(v0.x,wq0.x, fmaf(v0.y,wq0.z, fmaf(v0.z,wq1.x, fmaf(v0.w,wq1.z, a0.x))));
        a0.y = fmaf(v0.x,wq0.y, fmaf(v0.y,wq0.w, fmaf(v0.z,wq1.y, fmaf(v0.w,wq1.w, a0.y))));
        a1.x = fmaf(v1.x,wq0.x, fmaf(v1.y,wq0.z, fmaf(v1.z,wq1.x, fmaf(v1.w,wq1.z, a1.x))));
        a1.y = fmaf(v1.x,wq0.y, fmaf(v1.y,wq0.w, fmaf(v1.z,wq1.y, fmaf(v1.w,wq1.w, a1.y))));
        a2.x = fmaf(v2.x,wq0.x, fmaf(v2.y,wq0.z, fmaf(v2.z,wq1.x, fmaf(v2.w,wq1.z, a2.x))));
        a2.y = fmaf(v2.x,wq0.y, fmaf(v2.y,wq0.w, fmaf(v2.z,wq1.y, fmaf(v2.w,wq1.w, a2.y))));
        a3.x = fmaf(v3.x,wq0.x, fmaf(v3.y,wq0.z, fmaf(v3.z,wq1.x, fmaf(v3.w,wq1.z, a3.x))));
        a3.y = fmaf(v3.x,wq0.y, fmaf(v3.y,wq0.w, fmaf(v3.z,wq1.y, fmaf(v3.w,wq1.w, a3.y))));
      }
      *(f32x2*)&aap[w][0][l*2] = a0;
      *(f32x2*)&aap[w][1][l*2] = a1;
      *(f32x2*)&aap[w][2][l*2] = a2;
      *(f32x2*)&aap[w][3][l*2] = a3;
    }
    __syncthreads();

    // ---------- P2: e-partials over px rows
    {
      f32x4 aq = *(const f32x4*)&aap[0][p2b][p2kq*4];
      #pragma unroll
      for (int cs = 1; cs < 8; ++cs) aq += *(const f32x4*)&aap[cs][p2b][p2kq*4];
      #pragma unroll
      for (int i = 0; i < 16; ++i) {
        int n = p2ns*16 + i;
        f32x4 p = *(const f32x4*)&px[p2b][n][p2kq*4];
        float e = fmaf(fast_tanh(p.x+aq.x), w2v.x,
                  fmaf(fast_tanh(p.y+aq.y), w2v.y,
                  fmaf(fast_tanh(p.z+aq.z), w2v.z,
                       fast_tanh(p.w+aq.w) * w2v.w)));
        e += sx(e, 1);
        e += sx(e, 2);
        if ((p2kq & 3) == 0) epp[p2b][n][p2kq >> 2] = e;
      }
    }
    __syncthreads();

    // ---------- P3: softmax over n, x_tilde -> actc[b][n]
    if (tid < 256) {
      int b = tid >> 6, n = tid & 63;
      f32x4 e0 = *(const f32x4*)&epp[b][n][0];
      f32x4 e1 = *(const f32x4*)&epp[b][n][4];
      float e = ((e0.x+e0.y)+(e0.z+e0.w)) + ((e1.x+e1.y)+(e1.z+e1.w));
      float mx = e;
      #pragma unroll
      for (int m = 32; m >= 1; m >>= 1) mx = fmaxf(mx, sx(mx, m));
      float p = fast_exp(e - mx);
      float sm = p;
      #pragma unroll
      for (int m = 32; m >= 1; m >>= 1) sm += sx(sm, m);
      actc[b][n] = p * rcpf(sm) * xreg;
    }
    __syncthreads();

    // ---------- P4: gates; lane (cs,j) accumulates 4 batches x 4 gates
    {
      f32x4 a0, a1, a2, a3;
      a0 = 0.f; a1 = 0.f; a2 = 0.f; a3 = 0.f;
      #pragma unroll
      for (int g = 0; g < 12; ++g) {
        f32x4 v0 = *(const f32x4*)&actc[0][p4cs*48 + g*4];
        f32x4 v1 = *(const f32x4*)&actc[1][p4cs*48 + g*4];
        f32x4 v2 = *(const f32x4*)&actc[2][p4cs*48 + g*4];
        f32x4 v3 = *(const f32x4*)&actc[3][p4cs*48 + g*4];
        #pragma unroll
        for (int ii = 0; ii < 4; ++ii) {
          f32x4 wq = *(const f32x4*)(p4w + (g*4 + ii)*2048);
          a0 += v0[ii] * wq;
          a1 += v1[ii] * wq;
          a2 += v2[ii] * wq;
          a3 += v3[ii] * wq;
        }
      }
      // reduce over 4 c-slices (adjacent lanes; DPP)
      a0 += sx4(a0,1); a0 += sx4(a0,2);
      a1 += sx4(a1,1); a1 += sx4(a1,2);
      a2 += sx4(a2,1); a2 += sx4(a2,2);
      a3 += sx4(a3,1); a3 += sx4(a3,2);
      f32x4 gv = (p4cs == 0) ? a0 : (p4cs == 1) ? a1 : (p4cs == 2) ? a2 : a3;
      float ig = fast_sig (gv.x + bq0);
      float fg = fast_sig (gv.y + bq1);
      float gg = fast_tanh(gv.z + bq2);
      float og = fast_sig (gv.w + bq3);
      cre = fmaf(fg, cre, ig*gg);
      hn  = og * fast_tanh(cre);
    }
    __syncthreads();          // all reads of old state done

    // ---------- publish new state
    csd[p4cs][p4j] = cre;
    actc[p4cs][64 + p4j] = hn;
    __syncthreads();
  }

  // epilogue: last output row
  out[(b0+ob)*16384 + 127L*128 + oj] = actc[ob][64 + oj];
}

extern "C" void kernel_launch(void* const* d_in, const int* in_sizes, int n_in,
                              void* d_out, int out_size, void* d_ws, size_t ws_size,
                              hipStream_t stream) {
  const float* X   = (const float*)d_in[0];
  const float* Wat = (const float*)d_in[1];
  const float* b1  = (const float*)d_in[2];
  const float* w2  = (const float*)d_in[3];
  const float* Wih = (const float*)d_in[5];
  const float* Whh = (const float*)d_in[6];
  const float* bih = (const float*)d_in[7];
  const float* bhh = (const float*)d_in[8];
  float* out  = (float*)d_out;
  float* Wt   = (float*)d_ws;            // 16384
  float* W1P  = Wt + 16384;              // 32768
  float* Wp4  = W1P + 32768;             // 98304
  float* prex = Wp4 + 98304;             // 16777216

  k0_wt  <<<64,  256, 0, stream>>>(Wat, Wt);
  k0_w1p <<<128, 256, 0, stream>>>(Wat, W1P);
  k0_wp4 <<<384, 256, 0, stream>>>(Wih, Whh, Wp4);
  k1_prex<<<2048,256, 0, stream>>>(X, Wt, b1, prex);
  k2_lstm<<<512, 512, 0, stream>>>(X, W1P, Wp4, w2, bih, bhh, prex, out);
}

// Round 8
// 3468.637 us; speedup vs baseline: 1.4976x; 1.4976x over previous
//
#include <hip/hip_runtime.h>

// B=2048, T=128, N=64, H=128
// inputs: 0 X(2048,128,64) 1 W_attn1(128,384) 2 b_attn1(128) 3 w_attn2(128)
//         4 b_attn2(1)[unused] 5 W_ih(512,64) 6 W_hh(512,128) 7 b_ih(512) 8 b_hh(512)
// output: (2048,128,128) f32
// ws (floats): Wt[128][128] @0 | W1T[256][128] @16384 | WcT[192][512] @49152 | prex @147456
//
// R8: R5's proven-cache-hot global access shapes (scalar 4B/lane weight loads,
// 256B/wave segments, W1T/WcT layouts) kept byte-identical. Structural change:
// 2 batches/block, 1024 blocks, ~74.5 KB LDS -> 2 blocks/CU (16 waves) so two
// independent blocks overlap each other's stalls. P1b merged into P2; epp+DPP
// k-reduce; px linear. (R6/R7 lesson: vector weight loads at 1 block/CU broke
// the cache regime -> 8 GB HBM; conflicts were never material.)

typedef float f32x4 __attribute__((ext_vector_type(4)));

#define LOG2E 1.44269504088896340736f
__device__ __forceinline__ float rcpf(float x){ return __builtin_amdgcn_rcpf(x); }
__device__ __forceinline__ float fast_exp(float x){ return __builtin_exp2f(x * LOG2E); }
__device__ __forceinline__ float fast_tanh(float x){
  float e = __builtin_exp2f(x * (2.0f * LOG2E));
  return 1.0f - 2.0f * rcpf(e + 1.0f);
}
__device__ __forceinline__ float fast_sig(float x){
  float e = __builtin_exp2f(x * (-LOG2E));
  return rcpf(1.0f + e);
}
__device__ __forceinline__ float sx(float v, int m){ return __shfl_xor(v, m, 64); }

// ---- packs (identical to R5) ----
__global__ __launch_bounds__(256) void k0_wt(const float* __restrict__ Wat, float* __restrict__ Wt){
  int idx = blockIdx.x*256 + threadIdx.x;   // 16384
  int t = idx >> 7, k = idx & 127;
  Wt[idx] = Wat[k*384 + 256 + t];
}
__global__ __launch_bounds__(256) void k0_w1t(const float* __restrict__ Wat, float* __restrict__ W1T){
  int idx = blockIdx.x*256 + threadIdx.x;   // 32768 : W1T[c][k] = Wat[k][c]
  int c = idx >> 7, k = idx & 127;
  W1T[idx] = Wat[k*384 + c];
}
__global__ __launch_bounds__(256) void k0_wct(const float* __restrict__ Wih, const float* __restrict__ Whh,
                                              float* __restrict__ WcT){
  int idx = blockIdx.x*256 + threadIdx.x;   // 98304 : WcT[c][g]
  int c = idx >> 9, g = idx & 511;
  WcT[idx] = (c < 64) ? Wih[g*64 + c] : Whh[g*128 + (c-64)];
}

// ---- k1: prex[b][n][k] = sum_t X[b][t][n]*W1x[k][t] + b1[k]  (identical to R5) ----
__global__ __launch_bounds__(256) void k1_prex(const float* __restrict__ X,
                                               const float* __restrict__ Wt,
                                               const float* __restrict__ b1,
                                               float* __restrict__ prex){
  __shared__ float Xs[128][64];
  const int tid = threadIdx.x;
  const long b = blockIdx.x;
  {
    const float4* X4 = (const float4*)(X + b*8192);
    float4* Xs4 = (float4*)&Xs[0][0];
    #pragma unroll
    for (int i=0;i<8;i++) Xs4[tid + i*256] = X4[tid + i*256];
  }
  __syncthreads();
  const int nq = tid >> 4, kq = tid & 15;
  float acc[4][8];
  #pragma unroll
  for (int n=0;n<4;n++)
    #pragma unroll
    for (int k=0;k<8;k++) acc[n][k]=0.f;
  #pragma unroll 4
  for (int t=0;t<128;t++){
    float4 w0 = *(const float4*)(Wt + t*128 + kq*8);
    float4 w1 = *(const float4*)(Wt + t*128 + kq*8 + 4);
    float4 xv = *(const float4*)&Xs[t][nq*4];
    float wv[8] = {w0.x,w0.y,w0.z,w0.w,w1.x,w1.y,w1.z,w1.w};
    float xa[4] = {xv.x,xv.y,xv.z,xv.w};
    #pragma unroll
    for (int n=0;n<4;n++)
      #pragma unroll
      for (int k=0;k<8;k++) acc[n][k] = fmaf(xa[n], wv[k], acc[n][k]);
  }
  float4 bv0 = *(const float4*)(b1 + kq*8);
  float4 bv1 = *(const float4*)(b1 + kq*8 + 4);
  #pragma unroll
  for (int n=0;n<4;n++){
    float* dst = prex + (b*64 + nq*4 + n)*128 + kq*8;
    *(float4*)(dst)   = make_float4(acc[n][0]+bv0.x, acc[n][1]+bv0.y,
                                    acc[n][2]+bv0.z, acc[n][3]+bv0.w);
    *(float4*)(dst+4) = make_float4(acc[n][4]+bv1.x, acc[n][5]+bv1.y,
                                    acc[n][6]+bv1.z, acc[n][7]+bv1.w);
  }
}

// ---- k2: 1024 blocks x 512 threads, 2 batches/block, 2 blocks/CU ----
__global__ __launch_bounds__(512, 2)
void k2_lstm(const float* __restrict__ X,
             const float* __restrict__ W1T,
             const float* __restrict__ WcT,
             const float* __restrict__ w2,
             const float* __restrict__ bih,
             const float* __restrict__ bhh,
             const float* __restrict__ prex,
             float* __restrict__ out)
{
  const int tid = threadIdx.x;
  const long b0 = (long)blockIdx.x * 2;

  __shared__ float px[2][64][128];   // 64 KB, linear
  __shared__ union {
    float aap[4][2][128];            // P1 partials [cs][b][k]  4 KB
    float gp[2][512];                // P4 gate sums [b][g]     4 KB
  } u;
  __shared__ float epp[2][64][8];    // P2 partials             4 KB
  __shared__ float xt[2][64];        // x_tilde                 0.5 KB
  __shared__ float hsd[2][128];      // h state                 1 KB
  __shared__ float csd[2][128];      // c state                 1 KB

  // ---- px slice -> LDS (coalesced, linear)
  {
    const f32x4* pg = (const f32x4*)prex + b0*2048;
    f32x4* pl = (f32x4*)&px[0][0][0];
    #pragma unroll
    for (int i = 0; i < 8; ++i) pl[tid + i*512] = pg[tid + i*512];
  }
  if (tid < 256) { int b = tid>>7, j = tid&127; hsd[b][j]=0.f; csd[b][j]=0.f; }

  // ---- role constants
  // P1 (R5 shape): cs = tid>>7 (4 slices of 64 c), k = tid&127
  const int p1_cs = tid >> 7, p1_k = tid & 127;
  const float* p1_w = W1T + (p1_cs*64)*128 + p1_k;   // scalar loads, 256B/wave
  const float* p1_hc = (p1_cs < 2) ? &hsd[0][0] : &csd[0][0];
  const int p1_off = (p1_cs & 1) * 64;

  // P2: b = tid>>8, ns = (tid>>5)&7 (8 n's each), kq = tid&31
  const int p2b = tid >> 8, p2ns = (tid >> 5) & 7, p2kq = tid & 31;
  const f32x4 w2v = *(const f32x4*)(w2 + p2kq*4);

  // P4 (R5 shape): thread = one gate g, scalar stride-512 loads (256B/wave)
  const float* p4_w = WcT + tid;

  // P5: tid<256 -> (b, j)
  const int o_b = tid >> 7, o_j = tid & 127;
  const float bl0 = bih[o_j]       + bhh[o_j];
  const float bl1 = bih[o_j + 128] + bhh[o_j + 128];
  const float bl2 = bih[o_j + 256] + bhh[o_j + 256];
  const float bl3 = bih[o_j + 384] + bhh[o_j + 384];

  __syncthreads();

  for (int t = 0; t < 128; ++t) {
    // ---------- P1: aap[cs][b][k] = sum_{c in slice} hc[b][c] * W1[c][k]
    {
      float a0 = 0.f, a1 = 0.f;
      #pragma unroll 2
      for (int cc = 0; cc < 64; cc += 4) {
        float w0 = p1_w[(cc+0)*128];
        float w1 = p1_w[(cc+1)*128];
        float w2_ = p1_w[(cc+2)*128];
        float w3 = p1_w[(cc+3)*128];
        f32x4 h0 = *(const f32x4*)(p1_hc + 0*128 + p1_off + cc);
        f32x4 h1 = *(const f32x4*)(p1_hc + 1*128 + p1_off + cc);
        a0 = fmaf(h0.x,w0, fmaf(h0.y,w1, fmaf(h0.z,w2_, fmaf(h0.w,w3, a0))));
        a1 = fmaf(h1.x,w0, fmaf(h1.y,w1, fmaf(h1.z,w2_, fmaf(h1.w,w3, a1))));
      }
      u.aap[p1_cs][0][p1_k] = a0;
      u.aap[p1_cs][1][p1_k] = a1;
    }
    __syncthreads();

    // ---------- P2: epp[b][n][kq8] = sum_{16k} tanh(px+aa)*w2  (aa summed inline)
    {
      f32x4 aq = *(const f32x4*)&u.aap[0][p2b][p2kq*4];
      #pragma unroll
      for (int cs = 1; cs < 4; ++cs) aq += *(const f32x4*)&u.aap[cs][p2b][p2kq*4];
      #pragma unroll
      for (int i = 0; i < 8; ++i) {
        int n = p2ns*8 + i;
        f32x4 p = *(const f32x4*)&px[p2b][n][p2kq*4];
        float e = fmaf(fast_tanh(p.x+aq.x), w2v.x,
                  fmaf(fast_tanh(p.y+aq.y), w2v.y,
                  fmaf(fast_tanh(p.z+aq.z), w2v.z,
                       fast_tanh(p.w+aq.w) * w2v.w)));
        e += sx(e, 1);
        e += sx(e, 2);
        if ((p2kq & 3) == 0) epp[p2b][n][p2kq >> 2] = e;
      }
    }
    __syncthreads();

    // ---------- P3: softmax over n (one wave per b), x_tilde
    if (tid < 128) {
      int b = tid >> 6, n = tid & 63;
      f32x4 e0 = *(const f32x4*)&epp[b][n][0];
      f32x4 e1 = *(const f32x4*)&epp[b][n][4];
      float e = ((e0.x+e0.y)+(e0.z+e0.w)) + ((e1.x+e1.y)+(e1.z+e1.w));
      float mx = e;
      #pragma unroll
      for (int m = 32; m >= 1; m >>= 1) mx = fmaxf(mx, sx(mx, m));
      float p = fast_exp(e - mx);
      float sm = p;
      #pragma unroll
      for (int m = 32; m >= 1; m >>= 1) sm += sx(sm, m);
      xt[b][n] = p * rcpf(sm) * X[(b0+b)*8192 + (long)t*64 + n];
    }
    __syncthreads();

    // ---------- P4: gates[b][g]; thread = gate g, scalar stride-512 weight loads
    {
      float g0 = 0.f, g1 = 0.f;
      #pragma unroll 2
      for (int c = 0; c < 64; c += 4) {          // x-part
        float w0 = p4_w[(c+0)*512];
        float w1 = p4_w[(c+1)*512];
        float w2_ = p4_w[(c+2)*512];
        float w3 = p4_w[(c+3)*512];
        f32x4 a0 = *(const f32x4*)&xt[0][c];
        f32x4 a1 = *(const f32x4*)&xt[1][c];
        g0 = fmaf(a0.x,w0, fmaf(a0.y,w1, fmaf(a0.z,w2_, fmaf(a0.w,w3, g0))));
        g1 = fmaf(a1.x,w0, fmaf(a1.y,w1, fmaf(a1.z,w2_, fmaf(a1.w,w3, g1))));
      }
      #pragma unroll 2
      for (int c = 0; c < 128; c += 4) {         // h-part
        float w0 = p4_w[(64+c+0)*512];
        float w1 = p4_w[(64+c+1)*512];
        float w2_ = p4_w[(64+c+2)*512];
        float w3 = p4_w[(64+c+3)*512];
        f32x4 a0 = *(const f32x4*)&hsd[0][c];
        f32x4 a1 = *(const f32x4*)&hsd[1][c];
        g0 = fmaf(a0.x,w0, fmaf(a0.y,w1, fmaf(a0.z,w2_, fmaf(a0.w,w3, g0))));
        g1 = fmaf(a1.x,w0, fmaf(a1.y,w1, fmaf(a1.z,w2_, fmaf(a1.w,w3, g1))));
      }
      u.gp[0][tid] = g0;
      u.gp[1][tid] = g1;
    }
    __syncthreads();

    // ---------- P5: pointwise LSTM + state + output
    if (tid < 256) {
      float s0 = u.gp[o_b][o_j]       + bl0;
      float s1 = u.gp[o_b][o_j + 128] + bl1;
      float s2 = u.gp[o_b][o_j + 256] + bl2;
      float s3 = u.gp[o_b][o_j + 384] + bl3;
      float ig = fast_sig(s0), fg = fast_sig(s1);
      float gg = fast_tanh(s2), og = fast_sig(s3);
      float cn = fmaf(fg, csd[o_b][o_j], ig*gg);
      float hn = og * fast_tanh(cn);
      csd[o_b][o_j] = cn;
      hsd[o_b][o_j] = hn;
      out[(b0+o_b)*16384 + (long)t*128 + o_j] = hn;
    }
    __syncthreads();
  }
}

extern "C" void kernel_launch(void* const* d_in, const int* in_sizes, int n_in,
                              void* d_out, int out_size, void* d_ws, size_t ws_size,
                              hipStream_t stream) {
  const float* X   = (const float*)d_in[0];
  const float* Wat = (const float*)d_in[1];
  const float* b1  = (const float*)d_in[2];
  const float* w2  = (const float*)d_in[3];
  const float* Wih = (const float*)d_in[5];
  const float* Whh = (const float*)d_in[6];
  const float* bih = (const float*)d_in[7];
  const float* bhh = (const float*)d_in[8];
  float* out  = (float*)d_out;
  float* Wt   = (float*)d_ws;            // 16384
  float* W1T  = Wt + 16384;              // 32768
  float* WcT  = W1T + 32768;             // 98304
  float* prex = WcT + 98304;             // 16777216

  k0_wt  <<<64,  256, 0, stream>>>(Wat, Wt);
  k0_w1t <<<128, 256, 0, stream>>>(Wat, W1T);
  k0_wct <<<384, 256, 0, stream>>>(Wih, Whh, WcT);
  k1_prex<<<2048,256, 0, stream>>>(X, Wt, b1, prex);
  k2_lstm<<<1024,512, 0, stream>>>(X, W1T, WcT, w2, bih, bhh, prex, out);
}

// Round 9
// 2777.040 us; speedup vs baseline: 1.8706x; 1.2490x over previous
//
#include <hip/hip_runtime.h>
#include <hip/hip_fp16.h>

// B=2048, T=128, N=64, H=128
// inputs: 0 X(2048,128,64) 1 W_attn1(128,384) 2 b_attn1(128) 3 w_attn2(128)
//         4 b_attn2(1)[unused] 5 W_ih(512,64) 6 W_hh(512,128) 7 b_ih(512) 8 b_hh(512)
// output: (2048,128,128) f32
// ws: Wt[128][128]f32 @0 | W1T[256][128]f32 @16384 | WcT[192][512]f32 @49152 | prex f16 @147456(float units)
//
// R9: R5's proven per-block shape (4 batches, scalar weight loads, 256B/wave
// segments) + 2 blocks/CU. Enabler: prex stored/staged as fp16 -> px LDS 64KB,
// block total 79KB -> two co-resident R5-shaped blocks overlap each other's
// latency. (R8 lesson: 2 batches/block doubled per-CU weight-load instructions
// and ate the TLP gain; R6/R7 lesson: do not change global access shapes.)

typedef float f32x4 __attribute__((ext_vector_type(4)));

#define LOG2E 1.44269504088896340736f
__device__ __forceinline__ float rcpf(float x){ return __builtin_amdgcn_rcpf(x); }
__device__ __forceinline__ float fast_exp(float x){ return __builtin_exp2f(x * LOG2E); }
__device__ __forceinline__ float fast_tanh(float x){
  float e = __builtin_exp2f(x * (2.0f * LOG2E));
  return 1.0f - 2.0f * rcpf(e + 1.0f);
}
__device__ __forceinline__ float fast_sig(float x){
  float e = __builtin_exp2f(x * (-LOG2E));
  return rcpf(1.0f + e);
}
__device__ __forceinline__ float sx(float v, int m){ return __shfl_xor(v, m, 64); }

// ---- packs (identical to R5/R8) ----
__global__ __launch_bounds__(256) void k0_wt(const float* __restrict__ Wat, float* __restrict__ Wt){
  int idx = blockIdx.x*256 + threadIdx.x;   // 16384
  int t = idx >> 7, k = idx & 127;
  Wt[idx] = Wat[k*384 + 256 + t];
}
__global__ __launch_bounds__(256) void k0_w1t(const float* __restrict__ Wat, float* __restrict__ W1T){
  int idx = blockIdx.x*256 + threadIdx.x;   // 32768 : W1T[c][k] = Wat[k][c]
  int c = idx >> 7, k = idx & 127;
  W1T[idx] = Wat[k*384 + c];
}
__global__ __launch_bounds__(256) void k0_wct(const float* __restrict__ Wih, const float* __restrict__ Whh,
                                              float* __restrict__ WcT){
  int idx = blockIdx.x*256 + threadIdx.x;   // 98304 : WcT[c][g]
  int c = idx >> 9, g = idx & 511;
  WcT[idx] = (c < 64) ? Wih[g*64 + c] : Whh[g*128 + (c-64)];
}

// ---- k1: prex[b][n][k] = f16( sum_t X[b][t][n]*W1x[k][t] + b1[k] ) ----
__global__ __launch_bounds__(256) void k1_prex(const float* __restrict__ X,
                                               const float* __restrict__ Wt,
                                               const float* __restrict__ b1,
                                               __half* __restrict__ prex){
  __shared__ float Xs[128][64];
  const int tid = threadIdx.x;
  const long b = blockIdx.x;
  {
    const float4* X4 = (const float4*)(X + b*8192);
    float4* Xs4 = (float4*)&Xs[0][0];
    #pragma unroll
    for (int i=0;i<8;i++) Xs4[tid + i*256] = X4[tid + i*256];
  }
  __syncthreads();
  const int nq = tid >> 4, kq = tid & 15;
  float acc[4][8];
  #pragma unroll
  for (int n=0;n<4;n++)
    #pragma unroll
    for (int k=0;k<8;k++) acc[n][k]=0.f;
  #pragma unroll 4
  for (int t=0;t<128;t++){
    float4 w0 = *(const float4*)(Wt + t*128 + kq*8);
    float4 w1 = *(const float4*)(Wt + t*128 + kq*8 + 4);
    float4 xv = *(const float4*)&Xs[t][nq*4];
    float wv[8] = {w0.x,w0.y,w0.z,w0.w,w1.x,w1.y,w1.z,w1.w};
    float xa[4] = {xv.x,xv.y,xv.z,xv.w};
    #pragma unroll
    for (int n=0;n<4;n++)
      #pragma unroll
      for (int k=0;k<8;k++) acc[n][k] = fmaf(xa[n], wv[k], acc[n][k]);
  }
  float4 bv0 = *(const float4*)(b1 + kq*8);
  float4 bv1 = *(const float4*)(b1 + kq*8 + 4);
  #pragma unroll
  for (int n=0;n<4;n++){
    __half* dst = prex + ((long)(b*64 + nq*4 + n))*128 + kq*8;
    union { __half2 h2[4]; uint4 u4; } pk;
    pk.h2[0] = __floats2half2_rn(acc[n][0]+bv0.x, acc[n][1]+bv0.y);
    pk.h2[1] = __floats2half2_rn(acc[n][2]+bv0.z, acc[n][3]+bv0.w);
    pk.h2[2] = __floats2half2_rn(acc[n][4]+bv1.x, acc[n][5]+bv1.y);
    pk.h2[3] = __floats2half2_rn(acc[n][6]+bv1.z, acc[n][7]+bv1.w);
    *(uint4*)dst = pk.u4;
  }
}

// ---- k2: 512 blocks x 512 threads, 4 batches/block, 2 blocks/CU ----
__global__ __launch_bounds__(512, 4)
void k2_lstm(const float* __restrict__ X,
             const float* __restrict__ W1T,
             const float* __restrict__ WcT,
             const float* __restrict__ w2,
             const float* __restrict__ bih,
             const float* __restrict__ bhh,
             const __half* __restrict__ prex,
             float* __restrict__ out)
{
  const int tid = threadIdx.x;
  const long b0 = (long)blockIdx.x * 4;

  __shared__ __half px[4][64][128];  // 64 KB fp16 px slice, linear
  __shared__ union {
    float aap[4][4][128];            // P1 partials [cs][b][k]  8 KB
    float gp[4][512];                // P4 gate sums [b][g]     8 KB
  } u;
  __shared__ float epp[4][64][2];    // P2 partials             2 KB
  __shared__ float xt[4][64];        // x_tilde                 1 KB
  __shared__ float hsd[4][128];      // h state                 2 KB
  __shared__ float csd[4][128];      // c state                 2 KB
  // total = 79 KB -> 2 blocks/CU

  // ---- px slice -> LDS (coalesced, linear, fp16)
  {
    const uint4* pg = (const uint4*)(prex + b0*8192);
    uint4* pl = (uint4*)&px[0][0][0];
    #pragma unroll
    for (int i = 0; i < 8; ++i) pl[tid + i*512] = pg[tid + i*512];
  }
  { int b = tid >> 7, j = tid & 127; hsd[b][j] = 0.f; csd[b][j] = 0.f; }

  // ---- role constants (R5 shapes)
  const int p1_cs = tid >> 7, p1_k = tid & 127;
  const float* p1_w = W1T + (p1_cs*64)*128 + p1_k;   // scalar loads, 256B/wave
  const float* p1_hc = (p1_cs < 2) ? &hsd[0][0] : &csd[0][0];
  const int p1_off = (p1_cs & 1) * 64;

  const int p2b = tid >> 7, p2ns = (tid >> 5) & 3, p2kq = tid & 31;
  const f32x4 w2v = *(const f32x4*)(w2 + p2kq*4);

  const float* p4_w = WcT + tid;                     // scalar stride-512, 256B/wave

  const int o_b = tid >> 7, o_j = tid & 127;
  const float bl0 = bih[o_j]       + bhh[o_j];
  const float bl1 = bih[o_j + 128] + bhh[o_j + 128];
  const float bl2 = bih[o_j + 256] + bhh[o_j + 256];
  const float bl3 = bih[o_j + 384] + bhh[o_j + 384];

  __syncthreads();

  for (int t = 0; t < 128; ++t) {
    // ---------- P1: aap[cs][b][k] = sum_{c in 64-slice} hc[b][c] * W1[c][k]
    {
      float a0 = 0.f, a1 = 0.f, a2 = 0.f, a3 = 0.f;
      #pragma unroll 2
      for (int cc = 0; cc < 64; cc += 4) {
        float w0 = p1_w[(cc+0)*128];
        float w1 = p1_w[(cc+1)*128];
        float w2_ = p1_w[(cc+2)*128];
        float w3 = p1_w[(cc+3)*128];
        f32x4 h0 = *(const f32x4*)(p1_hc + 0*128 + p1_off + cc);
        f32x4 h1 = *(const f32x4*)(p1_hc + 1*128 + p1_off + cc);
        f32x4 h2 = *(const f32x4*)(p1_hc + 2*128 + p1_off + cc);
        f32x4 h3 = *(const f32x4*)(p1_hc + 3*128 + p1_off + cc);
        a0 = fmaf(h0.x,w0, fmaf(h0.y,w1, fmaf(h0.z,w2_, fmaf(h0.w,w3, a0))));
        a1 = fmaf(h1.x,w0, fmaf(h1.y,w1, fmaf(h1.z,w2_, fmaf(h1.w,w3, a1))));
        a2 = fmaf(h2.x,w0, fmaf(h2.y,w1, fmaf(h2.z,w2_, fmaf(h2.w,w3, a2))));
        a3 = fmaf(h3.x,w0, fmaf(h3.y,w1, fmaf(h3.z,w2_, fmaf(h3.w,w3, a3))));
      }
      u.aap[p1_cs][0][p1_k] = a0;
      u.aap[p1_cs][1][p1_k] = a1;
      u.aap[p1_cs][2][p1_k] = a2;
      u.aap[p1_cs][3][p1_k] = a3;
    }
    __syncthreads();

    // ---------- P2: epp[b][n][kh] = sum_k tanh(px+aa)*w2 (aa summed inline, DPP reduce)
    {
      f32x4 aq = *(const f32x4*)&u.aap[0][p2b][p2kq*4];
      #pragma unroll
      for (int cs = 1; cs < 4; ++cs) aq += *(const f32x4*)&u.aap[cs][p2b][p2kq*4];
      #pragma unroll
      for (int i = 0; i < 16; ++i) {
        int n = p2ns*16 + i;
        const __half2* pp = (const __half2*)&px[p2b][n][p2kq*4];
        float2 f0 = __half22float2(pp[0]);
        float2 f1 = __half22float2(pp[1]);
        float e = fmaf(fast_tanh(f0.x+aq.x), w2v.x,
                  fmaf(fast_tanh(f0.y+aq.y), w2v.y,
                  fmaf(fast_tanh(f1.x+aq.z), w2v.z,
                       fast_tanh(f1.y+aq.w) * w2v.w)));
        e += sx(e, 1);
        e += sx(e, 2);
        e += sx(e, 4);
        e += sx(e, 8);
        if ((p2kq & 15) == 0) epp[p2b][n][p2kq >> 4] = e;
      }
    }
    __syncthreads();

    // ---------- P3: softmax over n (one wave per b), x_tilde
    if (tid < 256) {
      int b = tid >> 6, n = tid & 63;
      float e = epp[b][n][0] + epp[b][n][1];
      float mx = e;
      #pragma unroll
      for (int m = 32; m >= 1; m >>= 1) mx = fmaxf(mx, sx(mx, m));
      float p = fast_exp(e - mx);
      float sm = p;
      #pragma unroll
      for (int m = 32; m >= 1; m >>= 1) sm += sx(sm, m);
      xt[b][n] = p * rcpf(sm) * X[(b0+b)*8192 + (long)t*64 + n];
    }
    __syncthreads();

    // ---------- P4: gates[b][g]; thread = gate g, scalar stride-512 weight loads
    {
      float g0 = 0.f, g1 = 0.f, g2 = 0.f, g3 = 0.f;
      #pragma unroll 2
      for (int c = 0; c < 64; c += 4) {          // x-part
        float w0 = p4_w[(c+0)*512];
        float w1 = p4_w[(c+1)*512];
        float w2_ = p4_w[(c+2)*512];
        float w3 = p4_w[(c+3)*512];
        f32x4 a0 = *(const f32x4*)&xt[0][c];
        f32x4 a1 = *(const f32x4*)&xt[1][c];
        f32x4 a2 = *(const f32x4*)&xt[2][c];
        f32x4 a3 = *(const f32x4*)&xt[3][c];
        g0 = fmaf(a0.x,w0, fmaf(a0.y,w1, fmaf(a0.z,w2_, fmaf(a0.w,w3, g0))));
        g1 = fmaf(a1.x,w0, fmaf(a1.y,w1, fmaf(a1.z,w2_, fmaf(a1.w,w3, g1))));
        g2 = fmaf(a2.x,w0, fmaf(a2.y,w1, fmaf(a2.z,w2_, fmaf(a2.w,w3, g2))));
        g3 = fmaf(a3.x,w0, fmaf(a3.y,w1, fmaf(a3.z,w2_, fmaf(a3.w,w3, g3))));
      }
      #pragma unroll 2
      for (int c = 0; c < 128; c += 4) {         // h-part
        float w0 = p4_w[(64+c+0)*512];
        float w1 = p4_w[(64+c+1)*512];
        float w2_ = p4_w[(64+c+2)*512];
        float w3 = p4_w[(64+c+3)*512];
        f32x4 a0 = *(const f32x4*)&hsd[0][c];
        f32x4 a1 = *(const f32x4*)&hsd[1][c];
        f32x4 a2 = *(const f32x4*)&hsd[2][c];
        f32x4 a3 = *(const f32x4*)&hsd[3][c];
        g0 = fmaf(a0.x,w0, fmaf(a0.y,w1, fmaf(a0.z,w2_, fmaf(a0.w,w3, g0))));
        g1 = fmaf(a1.x,w0, fmaf(a1.y,w1, fmaf(a1.z,w2_, fmaf(a1.w,w3, g1))));
        g2 = fmaf(a2.x,w0, fmaf(a2.y,w1, fmaf(a2.z,w2_, fmaf(a2.w,w3, g2))));
        g3 = fmaf(a3.x,w0, fmaf(a3.y,w1, fmaf(a3.z,w2_, fmaf(a3.w,w3, g3))));
      }
      u.gp[0][tid] = g0;
      u.gp[1][tid] = g1;
      u.gp[2][tid] = g2;
      u.gp[3][tid] = g3;
    }
    __syncthreads();

    // ---------- P5: pointwise LSTM + state + output (all 512 threads)
    {
      float s0 = u.gp[o_b][o_j]       + bl0;
      float s1 = u.gp[o_b][o_j + 128] + bl1;
      float s2 = u.gp[o_b][o_j + 256] + bl2;
      float s3 = u.gp[o_b][o_j + 384] + bl3;
      float ig = fast_sig(s0), fg = fast_sig(s1);
      float gg = fast_tanh(s2), og = fast_sig(s3);
      float cn = fmaf(fg, csd[o_b][o_j], ig*gg);
      float hn = og * fast_tanh(cn);
      csd[o_b][o_j] = cn;
      hsd[o_b][o_j] = hn;
      out[(b0+o_b)*16384 + (long)t*128 + o_j] = hn;
    }
    __syncthreads();
  }
}

extern "C" void kernel_launch(void* const* d_in, const int* in_sizes, int n_in,
                              void* d_out, int out_size, void* d_ws, size_t ws_size,
                              hipStream_t stream) {
  const float* X   = (const float*)d_in[0];
  const float* Wat = (const float*)d_in[1];
  const float* b1  = (const float*)d_in[2];
  const float* w2  = (const float*)d_in[3];
  const float* Wih = (const float*)d_in[5];
  const float* Whh = (const float*)d_in[6];
  const float* bih = (const float*)d_in[7];
  const float* bhh = (const float*)d_in[8];
  float* out  = (float*)d_out;
  float*  Wt   = (float*)d_ws;              // 16384 f32
  float*  W1T  = Wt + 16384;                // 32768 f32
  float*  WcT  = W1T + 32768;               // 98304 f32
  __half* prex = (__half*)(WcT + 98304);    // 2048*64*128 f16

  k0_wt  <<<64,  256, 0, stream>>>(Wat, Wt);
  k0_w1t <<<128, 256, 0, stream>>>(Wat, W1T);
  k0_wct <<<384, 256, 0, stream>>>(Wih, Whh, WcT);
  k1_prex<<<2048,256, 0, stream>>>(X, Wt, b1, prex);
  k2_lstm<<<512, 512, 0, stream>>>(X, W1T, WcT, w2, bih, bhh, prex, out);
}

// Round 14
// 2277.126 us; speedup vs baseline: 2.2813x; 1.2195x over previous
//
#include <hip/hip_runtime.h>
#include <hip/hip_fp16.h>

// B=2048, T=128, N=64, H=128
// inputs: 0 X(2048,128,64) 1 W_attn1(128,384) 2 b_attn1(128) 3 w_attn2(128)
//         4 b_attn2(1)[unused] 5 W_ih(512,64) 6 W_hh(512,128) 7 b_ih(512) 8 b_hh(512)
// output: (2048,128,128) f32
//
// R14 = R13 kernels BYTE-IDENTICAL; only kernel_launch ws layout fixed.
// ROOT CAUSE of R10-R13 failures: prex = 2048*64*128 = 16,777,216 halfs
// (8,388,608 f32 units), but layouts since R10 budgeted 2,097,152 halfs and
// placed packed weights INSIDE prex's true extent -> k1_prex clobbered them
// (launch order: packs, k1, k2). Deterministic ~1.09 error in all variants,
// regardless of MFMA/dot2 - the bisect variable was never isolated.
// Fixed layout (f32 units): Wt @0 (16384) | w1q @16384 (16384) | wcq @32768
// (49152) | prexH @81920 (8388608) -> ~34 MB total, prex at the END.

typedef float f32x4 __attribute__((ext_vector_type(4)));
typedef _Float16 f16x8 __attribute__((ext_vector_type(8)));
typedef _Float16 f16x4 __attribute__((ext_vector_type(4)));
typedef _Float16 f16x2 __attribute__((ext_vector_type(2)));

#define LOG2E 1.44269504088896340736f
__device__ __forceinline__ float rcpf(float x){ return __builtin_amdgcn_rcpf(x); }
__device__ __forceinline__ float fast_exp(float x){ return __builtin_exp2f(x * LOG2E); }
__device__ __forceinline__ float fast_tanh(float x){
  float e = __builtin_exp2f(x * (2.0f * LOG2E));
  return 1.0f - 2.0f * rcpf(e + 1.0f);
}
__device__ __forceinline__ float fast_sig(float x){
  float e = __builtin_exp2f(x * (-LOG2E));
  return rcpf(1.0f + e);
}
__device__ __forceinline__ float sx(float v, int m){ return __shfl_xor(v, m, 64); }

// 2-way f16 dot with f32 accumulate (v_dot2_f32_f16)
__device__ __forceinline__ float dot2(f16x2 a, f16x2 b, float acc){
#if __has_builtin(__builtin_amdgcn_fdot2)
  return __builtin_amdgcn_fdot2(a, b, acc, false);
#else
  return acc + (float)a[0]*(float)b[0] + (float)a[1]*(float)b[1];
#endif
}
__device__ __forceinline__ f16x2 pr4(f16x4 v, int i){ f16x2 r; r[0]=v[2*i]; r[1]=v[2*i+1]; return r; }
__device__ __forceinline__ f16x2 pr8(f16x8 v, int i){ f16x2 r; r[0]=v[2*i]; r[1]=v[2*i+1]; return r; }

// ---- k0_wt: Wt[t][k] = W1x[k][t] (for k1) ----
__global__ __launch_bounds__(256) void k0_wt(const float* __restrict__ Wat, float* __restrict__ Wt){
  int idx = blockIdx.x*256 + threadIdx.x;   // 16384
  int t = idx >> 7, k = idx & 127;
  Wt[idx] = Wat[k*384 + 256 + t];
}
// ---- k0_w1q: quad-pack W1=[W1h|W1s]^T: w1q[((c>>2)*128 + k)*4 + (c&3)] = Wat[k][c], c in [0,256)
__global__ __launch_bounds__(256) void k0_w1q(const float* __restrict__ Wat, _Float16* __restrict__ w1q){
  int idx = blockIdx.x*256 + threadIdx.x;   // 32768
  int c = idx >> 7, k = idx & 127;
  w1q[((c>>2)*128 + k)*4 + (c&3)] = (_Float16)Wat[k*384 + c];
}
// ---- k0_wcq: quad-pack Wc=[Wih|Whh]^T: wcq[((c>>2)*512 + g)*4 + (c&3)], c in [0,192), g in [0,512)
__global__ __launch_bounds__(256) void k0_wcq(const float* __restrict__ Wih, const float* __restrict__ Whh,
                                              _Float16* __restrict__ wcq){
  int idx = blockIdx.x*256 + threadIdx.x;   // 98304
  int c = idx >> 9, g = idx & 511;
  float v = (c < 64) ? Wih[g*64 + c] : Whh[g*128 + (c-64)];
  wcq[((c>>2)*512 + g)*4 + (c&3)] = (_Float16)v;
}

// ---- k1: prex[b][n][k] = f16( sum_t X[b][t][n]*W1x[k][t] + b1[k] )  (R9-identical)
__global__ __launch_bounds__(256) void k1_prex(const float* __restrict__ X,
                                               const float* __restrict__ Wt,
                                               const float* __restrict__ b1,
                                               __half* __restrict__ prex){
  __shared__ float Xs[128][64];
  const int tid = threadIdx.x;
  const long b = blockIdx.x;
  {
    const float4* X4 = (const float4*)(X + b*8192);
    float4* Xs4 = (float4*)&Xs[0][0];
    #pragma unroll
    for (int i=0;i<8;i++) Xs4[tid + i*256] = X4[tid + i*256];
  }
  __syncthreads();
  const int nq = tid >> 4, kq = tid & 15;
  float acc[4][8];
  #pragma unroll
  for (int n=0;n<4;n++)
    #pragma unroll
    for (int k=0;k<8;k++) acc[n][k]=0.f;
  #pragma unroll 4
  for (int t=0;t<128;t++){
    float4 w0 = *(const float4*)(Wt + t*128 + kq*8);
    float4 w1 = *(const float4*)(Wt + t*128 + kq*8 + 4);
    float4 xv = *(const float4*)&Xs[t][nq*4];
    float wv[8] = {w0.x,w0.y,w0.z,w0.w,w1.x,w1.y,w1.z,w1.w};
    float xa[4] = {xv.x,xv.y,xv.z,xv.w};
    #pragma unroll
    for (int n=0;n<4;n++)
      #pragma unroll
      for (int k=0;k<8;k++) acc[n][k] = fmaf(xa[n], wv[k], acc[n][k]);
  }
  float4 bv0 = *(const float4*)(b1 + kq*8);
  float4 bv1 = *(const float4*)(b1 + kq*8 + 4);
  #pragma unroll
  for (int n=0;n<4;n++){
    __half* dst = prex + ((long)(b*64 + nq*4 + n))*128 + kq*8;
    union { __half2 h2[4]; uint4 u4; } pk;
    pk.h2[0] = __floats2half2_rn(acc[n][0]+bv0.x, acc[n][1]+bv0.y);
    pk.h2[1] = __floats2half2_rn(acc[n][2]+bv0.z, acc[n][3]+bv0.w);
    pk.h2[2] = __floats2half2_rn(acc[n][4]+bv1.x, acc[n][5]+bv1.y);
    pk.h2[3] = __floats2half2_rn(acc[n][6]+bv1.z, acc[n][7]+bv1.w);
    *(uint4*)dst = pk.u4;
  }
}

// ---- k2: 512 blocks x 512 threads, 4 batches/block, 2 blocks/CU ----
__global__ __launch_bounds__(512, 4)
void k2_lstm(const float* __restrict__ X,
             const _Float16* __restrict__ w1q,
             const _Float16* __restrict__ wcq,
             const float* __restrict__ w2,
             const float* __restrict__ bih,
             const float* __restrict__ bhh,
             const __half* __restrict__ prex,
             float* __restrict__ out)
{
  const int tid = threadIdx.x;
  const long b0 = (long)blockIdx.x * 4;

  __shared__ __half px[4][64][128];  // 64 KB fp16 px slice (R9)
  __shared__ union {
    float aap[4][4][128];            // P1 partials [cs][b][k]  8 KB
    float gp[4][512];                // P4 gate sums [b][g]
  } u;
  __shared__ float epp[256][2];      // P2 partials             2 KB
  __shared__ float csd[4][128];      // c state f32 (exact)     2 KB
  __shared__ alignas(16) _Float16 hcB[64][4][4]; // [c4][b][4]: c4<32 h-quads, >=32 c-quads  2 KB
  __shared__ alignas(16) _Float16 acB[48][4][4]; // [c4][b][4]: c4<16 xt-quads, >=16 h-quads 1.5 KB
  // total 81408 B -> 2 blocks/CU

  // ---- px slice -> LDS (coalesced, linear, fp16)
  {
    const uint4* pg = (const uint4*)(prex + b0*8192);
    uint4* pl = (uint4*)&px[0][0][0];
    #pragma unroll
    for (int i = 0; i < 8; ++i) pl[tid + i*512] = pg[tid + i*512];
  }
  { int b = tid >> 7, j = tid & 127; csd[b][j] = 0.f; }
  for (int i = tid; i < 64*4*4; i += 512) (&hcB[0][0][0])[i] = (_Float16)0.f;
  for (int i = tid; i < 48*4*4; i += 512) (&acB[0][0][0])[i] = (_Float16)0.f;

  // ---- role constants
  // P1: cs = 4 slices of 64 c (16 quads), k = unit
  const int p1_cs = tid >> 7, p1_k = tid & 127;
  const _Float16* p1_w = w1q + ((p1_cs*16)*128 + p1_k)*4;   // f16x4 / c4, 512B/wave

  // P2 (R9): b, 16-row group, k-quad
  const int p2b = tid >> 7, p2ns = (tid >> 5) & 3, p2kq = tid & 31;
  const f32x4 w2v = *(const f32x4*)(w2 + p2kq*4);

  // P4: thread = gate g
  const _Float16* p4_w = wcq + tid*4;                       // f16x4 / c4, 512B/wave

  // P5: (b, j)
  const int o_b = tid >> 7, o_j = tid & 127;
  const float bl0 = bih[o_j]       + bhh[o_j];
  const float bl1 = bih[o_j + 128] + bhh[o_j + 128];
  const float bl2 = bih[o_j + 256] + bhh[o_j + 256];
  const float bl3 = bih[o_j + 384] + bhh[o_j + 384];

  __syncthreads();

  for (int t = 0; t < 128; ++t) {
    // ---------- P1 (dot2): aap[cs][b][k] = sum_{c in 64-slice} hc[b][c] * W1[c][k]
    {
      float a0 = 0.f, a1 = 0.f, a2 = 0.f, a3 = 0.f;
      #pragma unroll
      for (int i = 0; i < 16; ++i) {
        f16x4 wq = *(const f16x4*)(p1_w + i*512);
        f16x2 w01 = pr4(wq, 0), w23 = pr4(wq, 1);
        f16x8 hA = *(const f16x8*)&hcB[p1_cs*16 + i][0][0];   // batches 0,1 (broadcast)
        f16x8 hB = *(const f16x8*)&hcB[p1_cs*16 + i][2][0];   // batches 2,3
        a0 = dot2(pr8(hA,0), w01, a0); a0 = dot2(pr8(hA,1), w23, a0);
        a1 = dot2(pr8(hA,2), w01, a1); a1 = dot2(pr8(hA,3), w23, a1);
        a2 = dot2(pr8(hB,0), w01, a2); a2 = dot2(pr8(hB,1), w23, a2);
        a3 = dot2(pr8(hB,2), w01, a3); a3 = dot2(pr8(hB,3), w23, a3);
      }
      u.aap[p1_cs][0][p1_k] = a0;
      u.aap[p1_cs][1][p1_k] = a1;
      u.aap[p1_cs][2][p1_k] = a2;
      u.aap[p1_cs][3][p1_k] = a3;
    }
    __syncthreads();

    // ---------- P2 (R9): epp = sum_k tanh(px+aa)*w2, aa summed inline, DPP+shfl reduce
    {
      f32x4 aq = *(const f32x4*)&u.aap[0][p2b][p2kq*4];
      #pragma unroll
      for (int cs = 1; cs < 4; ++cs) aq += *(const f32x4*)&u.aap[cs][p2b][p2kq*4];
      #pragma unroll
      for (int i = 0; i < 16; ++i) {
        int n = p2ns*16 + i;
        const __half2* pp = (const __half2*)&px[p2b][n][p2kq*4];
        float2 f0 = __half22float2(pp[0]);
        float2 f1 = __half22float2(pp[1]);
        float e = fmaf(fast_tanh(f0.x+aq.x), w2v.x,
                  fmaf(fast_tanh(f0.y+aq.y), w2v.y,
                  fmaf(fast_tanh(f1.x+aq.z), w2v.z,
                       fast_tanh(f1.y+aq.w) * w2v.w)));
        e += sx(e, 1);
        e += sx(e, 2);
        e += sx(e, 4);
        e += sx(e, 8);
        if ((p2kq & 15) == 0) epp[p2b*64 + n][p2kq >> 4] = e;
      }
    }
    __syncthreads();

    // ---------- P3 (R9): softmax over n (wave per b), x_tilde -> acB quads
    if (tid < 256) {
      int b = tid >> 6, n = tid & 63;
      float e = epp[tid][0] + epp[tid][1];
      float mx = e;
      #pragma unroll
      for (int m = 32; m >= 1; m >>= 1) mx = fmaxf(mx, sx(mx, m));
      float p = fast_exp(e - mx);
      float sm = p;
      #pragma unroll
      for (int m = 32; m >= 1; m >>= 1) sm += sx(sm, m);
      float xtv = p * rcpf(sm) * X[(b0+b)*8192 + (long)t*64 + n];
      acB[n>>2][b][n&3] = (_Float16)xtv;
    }
    __syncthreads();

    // ---------- P4 (dot2): gates[b][g]; thread = gate g over 48 c-quads
    {
      float g0 = 0.f, g1 = 0.f, g2 = 0.f, g3 = 0.f;
      #pragma unroll 8
      for (int c4 = 0; c4 < 48; ++c4) {
        f16x4 wq = *(const f16x4*)(p4_w + c4*2048);
        f16x2 w01 = pr4(wq, 0), w23 = pr4(wq, 1);
        f16x8 aA = *(const f16x8*)&acB[c4][0][0];   // batches 0,1 (broadcast)
        f16x8 aB = *(const f16x8*)&acB[c4][2][0];   // batches 2,3
        g0 = dot2(pr8(aA,0), w01, g0); g0 = dot2(pr8(aA,1), w23, g0);
        g1 = dot2(pr8(aA,2), w01, g1); g1 = dot2(pr8(aA,3), w23, g1);
        g2 = dot2(pr8(aB,0), w01, g2); g2 = dot2(pr8(aB,1), w23, g2);
        g3 = dot2(pr8(aB,2), w01, g3); g3 = dot2(pr8(aB,3), w23, g3);
      }
      u.gp[0][tid] = g0;
      u.gp[1][tid] = g1;
      u.gp[2][tid] = g2;
      u.gp[3][tid] = g3;
    }
    __syncthreads();

    // ---------- P5 (R9): pointwise LSTM; c exact f32; publish f16 quads
    {
      float s0 = u.gp[o_b][o_j]       + bl0;
      float s1 = u.gp[o_b][o_j + 128] + bl1;
      float s2 = u.gp[o_b][o_j + 256] + bl2;
      float s3 = u.gp[o_b][o_j + 384] + bl3;
      float ig = fast_sig(s0), fg = fast_sig(s1);
      float gg = fast_tanh(s2), og = fast_sig(s3);
      float cn = fmaf(fg, csd[o_b][o_j], ig*gg);
      float hn = og * fast_tanh(cn);
      csd[o_b][o_j] = cn;
      hcB[o_j>>2][o_b][o_j&3]        = (_Float16)hn;   // h  (hc index o_j)
      hcB[32 + (o_j>>2)][o_b][o_j&3] = (_Float16)cn;   // c  (hc index 128+o_j)
      acB[16 + (o_j>>2)][o_b][o_j&3] = (_Float16)hn;   // h  (ac index 64+o_j)
      out[(b0+o_b)*16384 + (long)t*128 + o_j] = hn;
    }
    __syncthreads();
  }
}

extern "C" void kernel_launch(void* const* d_in, const int* in_sizes, int n_in,
                              void* d_out, int out_size, void* d_ws, size_t ws_size,
                              hipStream_t stream) {
  const float* X   = (const float*)d_in[0];
  const float* Wat = (const float*)d_in[1];
  const float* b1  = (const float*)d_in[2];
  const float* w2  = (const float*)d_in[3];
  const float* Wih = (const float*)d_in[5];
  const float* Whh = (const float*)d_in[6];
  const float* bih = (const float*)d_in[7];
  const float* bhh = (const float*)d_in[8];
  float* out  = (float*)d_out;

  // FIXED layout: prex (16,777,216 halfs = 8,388,608 f32) at the END.
  float*    Wt   = (float*)d_ws;                 // [0, 16384) f32
  _Float16* w1q  = (_Float16*)(Wt + 16384);      // [16384, 32768) f32 (32768 halfs)
  _Float16* wcq  = (_Float16*)(Wt + 32768);      // [32768, 81920) f32 (98304 halfs)
  __half*   prexH= (__half*)(Wt + 81920);        // [81920, 8470528) f32

  k0_wt  <<<64,  256, 0, stream>>>(Wat, Wt);
  k0_w1q <<<128, 256, 0, stream>>>(Wat, w1q);
  k0_wcq <<<384, 256, 0, stream>>>(Wih, Whh, wcq);
  k1_prex<<<2048,256, 0, stream>>>(X, Wt, b1, prexH);
  k2_lstm<<<512, 512, 0, stream>>>(X, w1q, wcq, w2, bih, bhh, prexH, out);
}

// Round 15
// 1632.972 us; speedup vs baseline: 3.1812x; 1.3945x over previous
//
#include <hip/hip_runtime.h>
#include <hip/hip_fp16.h>

// B=2048, T=128, N=64, H=128
// inputs: 0 X(2048,128,64) 1 W_attn1(128,384) 2 b_attn1(128) 3 w_attn2(128)
//         4 b_attn2(1)[unused] 5 W_ih(512,64) 6 W_hh(512,128) 7 b_ih(512) 8 b_hh(512)
// output: (2048,128,128) f32
//
// R15: full-MFMA k2 on the FIXED ws layout (R14 root cause: prex extent was
// under-budgeted 8x since R10; packed weights were clobbered by k1 -> the
// ~1.09 failures were never MFMA's fault). Structure: R10, simplified:
//  - both GEMVs on mfma_f32_16x16x32_f16; weight B-frags in VGPRs (load once).
//  - plain f16 state (R14: absmax sits at bf16 comparison floor; no hi/lo).
//  - padded LDS rows (264/200 halfs -> 2-way bank conflicts, free) - no swizzle.
//  - px slice in registers; c-recurrence exact f32 in register.
// ws (f32 units): Wt @0 | p1p @16384 | p4p @32768 | prexH @81920 (8388608, END)

typedef float f32x4 __attribute__((ext_vector_type(4)));
typedef _Float16 f16x8 __attribute__((ext_vector_type(8)));
typedef _Float16 f16x4 __attribute__((ext_vector_type(4)));

#define LOG2E 1.44269504088896340736f
__device__ __forceinline__ float rcpf(float x){ return __builtin_amdgcn_rcpf(x); }
__device__ __forceinline__ float fast_exp(float x){ return __builtin_exp2f(x * LOG2E); }
__device__ __forceinline__ float fast_tanh(float x){
  float e = __builtin_exp2f(x * (2.0f * LOG2E));
  return 1.0f - 2.0f * rcpf(e + 1.0f);
}
__device__ __forceinline__ float fast_sig(float x){
  float e = __builtin_exp2f(x * (-LOG2E));
  return rcpf(1.0f + e);
}
__device__ __forceinline__ float sx(float v, int m){ return __shfl_xor(v, m, 64); }

// ---- k0_wt: Wt[t][k] = W1x[k][t] (for k1) ----
__global__ __launch_bounds__(256) void k0_wt(const float* __restrict__ Wat, float* __restrict__ Wt){
  int idx = blockIdx.x*256 + threadIdx.x;   // 16384
  int t = idx >> 7, k = idx & 127;
  Wt[idx] = Wat[k*384 + 256 + t];
}
// ---- k0_p1p: frag pack of W1=[W1h|W1s]^T (256->128) for MFMA B.
// B slot map: lane l holds col=w*16+(l&15), k-slot c = f*32 + (l>>4)*8 + e.
__global__ __launch_bounds__(256) void k0_p1p(const float* __restrict__ Wat, _Float16* __restrict__ p1p){
  int idx = blockIdx.x*256 + threadIdx.x;   // 32768 = 8w x 8f x 64l x 8e
  int e = idx & 7, l = (idx>>3) & 63, f = (idx>>9) & 7, w = idx >> 12;
  int col = w*16 + (l & 15);                // attn unit (0..127)
  int c   = f*32 + ((l>>4)&3)*8 + e;        // contraction (0..255): [h|c]
  p1p[idx] = (_Float16)Wat[col*384 + c];
}
// ---- k0_p4p: frag pack of Wc=[Wih|Whh]^T (192->512); wave w -> tiles 4w..4w+3
__global__ __launch_bounds__(256) void k0_p4p(const float* __restrict__ Wih, const float* __restrict__ Whh,
                                              _Float16* __restrict__ p4p){
  int idx = blockIdx.x*256 + threadIdx.x;   // 98304 = 8w x 24fi x 64l x 8e
  int e = idx & 7, l = (idx>>3) & 63, r = idx >> 9;   // r in [0,192)
  int fi = r % 24, w = r / 24;
  int ti = fi / 6, ks = fi % 6;
  int g = (w*4 + ti)*16 + (l & 15);         // gate unit (0..511) = q*128+j
  int c = ks*32 + ((l>>4)&3)*8 + e;         // contraction (0..191): [xt|h]
  p4p[idx] = (_Float16)((c < 64) ? Wih[g*64 + c] : Whh[g*128 + (c-64)]);
}

// ---- k1: prex[b][n][k] = f16( sum_t X[b][t][n]*W1x[k][t] + b1[k] )  (R9-identical)
__global__ __launch_bounds__(256) void k1_prex(const float* __restrict__ X,
                                               const float* __restrict__ Wt,
                                               const float* __restrict__ b1,
                                               __half* __restrict__ prex){
  __shared__ float Xs[128][64];
  const int tid = threadIdx.x;
  const long b = blockIdx.x;
  {
    const float4* X4 = (const float4*)(X + b*8192);
    float4* Xs4 = (float4*)&Xs[0][0];
    #pragma unroll
    for (int i=0;i<8;i++) Xs4[tid + i*256] = X4[tid + i*256];
  }
  __syncthreads();
  const int nq = tid >> 4, kq = tid & 15;
  float acc[4][8];
  #pragma unroll
  for (int n=0;n<4;n++)
    #pragma unroll
    for (int k=0;k<8;k++) acc[n][k]=0.f;
  #pragma unroll 4
  for (int t=0;t<128;t++){
    float4 w0 = *(const float4*)(Wt + t*128 + kq*8);
    float4 w1 = *(const float4*)(Wt + t*128 + kq*8 + 4);
    float4 xv = *(const float4*)&Xs[t][nq*4];
    float wv[8] = {w0.x,w0.y,w0.z,w0.w,w1.x,w1.y,w1.z,w1.w};
    float xa[4] = {xv.x,xv.y,xv.z,xv.w};
    #pragma unroll
    for (int n=0;n<4;n++)
      #pragma unroll
      for (int k=0;k<8;k++) acc[n][k] = fmaf(xa[n], wv[k], acc[n][k]);
  }
  float4 bv0 = *(const float4*)(b1 + kq*8);
  float4 bv1 = *(const float4*)(b1 + kq*8 + 4);
  #pragma unroll
  for (int n=0;n<4;n++){
    __half* dst = prex + ((long)(b*64 + nq*4 + n))*128 + kq*8;
    union { __half2 h2[4]; uint4 u4; } pk;
    pk.h2[0] = __floats2half2_rn(acc[n][0]+bv0.x, acc[n][1]+bv0.y);
    pk.h2[1] = __floats2half2_rn(acc[n][2]+bv0.z, acc[n][3]+bv0.w);
    pk.h2[2] = __floats2half2_rn(acc[n][4]+bv1.x, acc[n][5]+bv1.y);
    pk.h2[3] = __floats2half2_rn(acc[n][6]+bv1.z, acc[n][7]+bv1.w);
    *(uint4*)dst = pk.u4;
  }
}

// ---- k2: 512 blocks x 512 threads, 4 batches/block, 1 block/CU (VGPR ~220) ----
__global__ __launch_bounds__(512, 2)
void k2_lstm(const float* __restrict__ X,
             const _Float16* __restrict__ p1p,
             const _Float16* __restrict__ p4p,
             const float* __restrict__ w2,
             const float* __restrict__ bih,
             const float* __restrict__ bhh,
             const __half* __restrict__ prex,
             float* __restrict__ out)
{
  const int tid = threadIdx.x;
  const long b0 = (long)blockIdx.x * 4;
  const int w = tid >> 6, l = tid & 63;

  // A tiles, rows = batches 0..3 (rows 4..15 stay zero). PADDED rows:
  // A1 264 halfs/row (132 dw -> 4-bank shift -> 2-way conflicts, free);
  // A4 200 halfs/row (100 dw -> same).
  __shared__ alignas(16) _Float16 A1[16*264];  // [h | c], K=256         8.25 KB
  __shared__ alignas(16) _Float16 A4[16*200];  // [xt | h], K=192        6.25 KB
  __shared__ float aa[4][128];       // attn pre-act (h,c part)          2 KB
  __shared__ float gp[4][512];       // gates                            8 KB
  __shared__ float epp[256][2];      // P2 partials                      2 KB
  // total ~27.5 KB

  for (int i = tid; i < 16*264; i += 512) A1[i] = (_Float16)0.f;
  for (int i = tid; i < 16*200; i += 512) A4[i] = (_Float16)0.f;

  // ---- weight fragments -> VGPRs (persist all 128 steps)
  f16x8 w1f[8];
  {
    const f16x8* p = (const f16x8*)p1p;
    #pragma unroll
    for (int f = 0; f < 8; ++f) w1f[f] = p[(w*8 + f)*64 + l];
  }
  f16x8 w4f[24];
  {
    const f16x8* p = (const f16x8*)p4p;
    #pragma unroll
    for (int f = 0; f < 24; ++f) w4f[f] = p[(w*24 + f)*64 + l];
  }

  // ---- px slice -> registers: thread = (b=p2b, 16-row group p2ns, k-quad kq)
  const int kq = tid & 31, p2ns = (tid >> 5) & 3, p2b = tid >> 7;
  f16x4 pxr[16];
  {
    const _Float16* pb = (const _Float16*)prex + ((b0 + p2b)*64 + p2ns*16)*128 + kq*4;
    #pragma unroll
    for (int i = 0; i < 16; ++i) pxr[i] = *(const f16x4*)(pb + i*128);
  }
  const f32x4 w2v = *(const f32x4*)(w2 + kq*4);

  // MFMA lane constants: arow = A-row this lane reads, ag = k-slot quarter
  const int arow = l & 15, ag = l >> 4;

  // P5 role: thread = (batch ob, unit oj)
  const int ob = tid >> 7, oj = tid & 127;
  const float bl0 = bih[oj]       + bhh[oj];
  const float bl1 = bih[oj + 128] + bhh[oj + 128];
  const float bl2 = bih[oj + 256] + bhh[oj + 256];
  const float bl3 = bih[oj + 384] + bhh[oj + 384];
  float cre = 0.f;          // exact f32 c-state

  __syncthreads();

  for (int t = 0; t < 128; ++t) {
    // ---------- P1 (MFMA): aa[4][128] = [h|c](4x256) @ W1; wave w -> cols w*16..+16
    {
      f32x4 acc = {0.f,0.f,0.f,0.f};
      const _Float16* Ab = A1 + arow*264 + ag*8;
      #pragma unroll
      for (int f = 0; f < 8; ++f) {
        f16x8 a = *(const f16x8*)(Ab + f*32);
        acc = __builtin_amdgcn_mfma_f32_16x16x32_f16(a, w1f[f], acc, 0, 0, 0);
      }
      if (l < 16) {   // D: col = l, row = v (batches 0..3)
        #pragma unroll
        for (int v = 0; v < 4; ++v) aa[v][w*16 + l] = acc[v];
      }
    }
    __syncthreads();

    // ---------- P2: e-partials; px in regs, tanh on VALU
    {
      f32x4 aq = *(const f32x4*)&aa[p2b][kq*4];
      #pragma unroll
      for (int i = 0; i < 16; ++i) {
        f16x4 p = pxr[i];
        float e = fmaf(fast_tanh((float)p[0] + aq.x), w2v.x,
                  fmaf(fast_tanh((float)p[1] + aq.y), w2v.y,
                  fmaf(fast_tanh((float)p[2] + aq.z), w2v.z,
                       fast_tanh((float)p[3] + aq.w) * w2v.w)));
        e += sx(e, 1);
        e += sx(e, 2);
        e += sx(e, 4);
        e += sx(e, 8);
        if ((kq & 15) == 0) epp[p2b*64 + p2ns*16 + i][kq >> 4] = e;
      }
    }
    __syncthreads();

    // ---------- P3: softmax over n (wave per b), x_tilde -> A4[b][n]
    if (tid < 256) {
      int b = tid >> 6, n = tid & 63;
      float e = epp[tid][0] + epp[tid][1];
      float mx = e;
      #pragma unroll
      for (int m = 32; m >= 1; m >>= 1) mx = fmaxf(mx, sx(mx, m));
      float p = fast_exp(e - mx);
      float sm = p;
      #pragma unroll
      for (int m = 32; m >= 1; m >>= 1) sm += sx(sm, m);
      float xtv = p * rcpf(sm) * X[(b0+b)*8192 + (long)t*64 + n];
      A4[b*200 + n] = (_Float16)xtv;
    }
    __syncthreads();

    // ---------- P4 (MFMA): gates[4][512] = A4(4x192) @ Wc; wave w -> tiles 4w..4w+3
    {
      f32x4 c0 = {0.f,0.f,0.f,0.f}, c1 = c0, c2 = c0, c3 = c0;
      const _Float16* Ab = A4 + arow*200 + ag*8;
      #pragma unroll
      for (int ks = 0; ks < 6; ++ks) {
        f16x8 a = *(const f16x8*)(Ab + ks*32);
        c0 = __builtin_amdgcn_mfma_f32_16x16x32_f16(a, w4f[ks],      c0, 0, 0, 0);
        c1 = __builtin_amdgcn_mfma_f32_16x16x32_f16(a, w4f[6  + ks], c1, 0, 0, 0);
        c2 = __builtin_amdgcn_mfma_f32_16x16x32_f16(a, w4f[12 + ks], c2, 0, 0, 0);
        c3 = __builtin_amdgcn_mfma_f32_16x16x32_f16(a, w4f[18 + ks], c3, 0, 0, 0);
      }
      if (l < 16) {
        #pragma unroll
        for (int v = 0; v < 4; ++v) {
          gp[v][(w*4 + 0)*16 + l] = c0[v];
          gp[v][(w*4 + 1)*16 + l] = c1[v];
          gp[v][(w*4 + 2)*16 + l] = c2[v];
          gp[v][(w*4 + 3)*16 + l] = c3[v];
        }
      }
    }
    __syncthreads();

    // ---------- P5: pointwise LSTM; c exact f32 in reg; publish f16 state
    {
      float s0 = gp[ob][oj]       + bl0;
      float s1 = gp[ob][oj + 128] + bl1;
      float s2 = gp[ob][oj + 256] + bl2;
      float s3 = gp[ob][oj + 384] + bl3;
      float ig = fast_sig(s0), fg = fast_sig(s1);
      float gg = fast_tanh(s2), og = fast_sig(s3);
      cre = fmaf(fg, cre, ig*gg);
      float hn = og * fast_tanh(cre);
      _Float16 hh = (_Float16)hn;
      A1[ob*264 + oj]       = hh;               // h
      A1[ob*264 + 128 + oj] = (_Float16)cre;    // c
      A4[ob*200 + 64 + oj]  = hh;               // h
      out[(b0+ob)*16384 + (long)t*128 + oj] = hn;
    }
    __syncthreads();
  }
}

extern "C" void kernel_launch(void* const* d_in, const int* in_sizes, int n_in,
                              void* d_out, int out_size, void* d_ws, size_t ws_size,
                              hipStream_t stream) {
  const float* X   = (const float*)d_in[0];
  const float* Wat = (const float*)d_in[1];
  const float* b1  = (const float*)d_in[2];
  const float* w2  = (const float*)d_in[3];
  const float* Wih = (const float*)d_in[5];
  const float* Whh = (const float*)d_in[6];
  const float* bih = (const float*)d_in[7];
  const float* bhh = (const float*)d_in[8];
  float* out  = (float*)d_out;

  // FIXED layout: prex (16,777,216 halfs = 8,388,608 f32) at the END.
  float*    Wt   = (float*)d_ws;                 // [0, 16384) f32
  _Float16* p1p  = (_Float16*)(Wt + 16384);      // 32768 halfs -> [16384, 32768) f32
  _Float16* p4p  = (_Float16*)(Wt + 32768);      // 98304 halfs -> [32768, 81920) f32
  __half*   prexH= (__half*)(Wt + 81920);        // [81920, 8470528) f32

  k0_wt  <<<64,  256, 0, stream>>>(Wat, Wt);
  k0_p1p <<<128, 256, 0, stream>>>(Wat, p1p);
  k0_p4p <<<384, 256, 0, stream>>>(Wih, Whh, p4p);
  k1_prex<<<2048,256, 0, stream>>>(X, Wt, b1, prexH);
  k2_lstm<<<512, 512, 0, stream>>>(X, p1p, p4p, w2, bih, bhh, prexH, out);
}